// Round 1
// baseline (86.060 us; speedup 1.0000x reference)
//
#include <hip/hip_runtime.h>

// Chamfer distance via MFMA — R12: R11's row-min-only two-pass structure
// + async double-buffered LDS staging (global_load_lds width=16, counted
// vmcnt(4), raw s_barrier — T3/T4-lite per m97/m201 template).
// R11 was a 2-phase drain structure: per chunk, global->reg->ds_write->
// __syncthreads() (full vmcnt(0)+lgkmcnt(0) drain) left all waves stalled
// on ~300cy global latency 16x per block. Now chunk c+1's DMA is issued
// before computing chunk c; s_waitcnt vmcnt(4) keeps 4 loads in flight
// across the barrier. Pipes: MFMA 6.8us, LDS-read 10.2us, VALU 3.5us.
// d2(i,j) = xsq_i + ysq_j - 2 x.y in one 32x32x16 bf16 MFMA via split-bf16
// K-slots (packing verified since R6, absmax 0.0):
//   A k0..15 = [xh0,xh1,xh2, xl0,xl1,xl2, xh0,xh1, xh2, xsqh,xsql, 1,1, 0,0,0]
//   B k0..15 = [-2yh0..2,   -2yh0..2,    -2yl0..2,     1,1, ysqh,ysql, 0,0,0]
// Zero atomics anywhere (R9 lesson).

typedef __attribute__((ext_vector_type(8))) short bf16x8;
typedef __attribute__((ext_vector_type(16))) float floatx16;

#define BB 16
#define NN 4096
#define T  256
#define NPTS (BB * NN)       // 65536 points per set
#define YC 512               // y per LDS chunk
#define NC (NN / YC)         // 8 chunks
#define XC 128               // x per block (4 waves x 32-row strip)
#define NXB (NN / XC)        // 32 x-blocks
#define NBLK (2 * BB * NXB)  // 1024 main blocks
#define ONEBF 0x3F80u

__device__ __forceinline__ unsigned int f2bf(float f) {
    unsigned int u = __float_as_uint(f);
    u += 0x7fffu + ((u >> 16) & 1u);     // RNE to bf16
    return u >> 16;
}
__device__ __forceinline__ float bf2f(unsigned int h) {
    return __uint_as_float(h << 16);
}

// async 16B global->LDS DMA (no VGPR round-trip; compiler never auto-emits)
__device__ __forceinline__ void gl_lds16(const uint4* g, uint4* l) {
    __builtin_amdgcn_global_load_lds(
        (const __attribute__((address_space(1))) void*)g,
        (__attribute__((address_space(3))) void*)l, 16, 0, 0);
}

// ---- prep: build 32B y-records for both point sets (set0=target, set1=pred)
__global__ __launch_bounds__(T) void chamfer_prep(
    const float* __restrict__ pred, const float* __restrict__ target,
    uint4* __restrict__ rec0, uint4* __restrict__ rec1)
{
    int g = blockIdx.x * T + threadIdx.x;        // 0 .. 2*NPTS-1
    int set = g >> 16;                           // /NPTS
    int idx = g & (NPTS - 1);
    const float* yp = (set ? pred : target) + (size_t)idx * 3;
    float y0 = yp[0], y1 = yp[1], y2 = yp[2];
    unsigned int h0 = f2bf(y0), h1 = f2bf(y1), h2 = f2bf(y2);
    unsigned int H0 = f2bf(-2.f * bf2f(h0));
    unsigned int H1 = f2bf(-2.f * bf2f(h1));
    unsigned int H2 = f2bf(-2.f * bf2f(h2));
    unsigned int L0 = f2bf(-2.f * (y0 - bf2f(h0)));
    unsigned int L1 = f2bf(-2.f * (y1 - bf2f(h1)));
    unsigned int L2 = f2bf(-2.f * (y2 - bf2f(h2)));
    float ysq = fmaf(y0, y0, fmaf(y1, y1, y2 * y2));
    unsigned int sh = f2bf(ysq);
    unsigned int sl = f2bf(ysq - bf2f(sh));
    rec0[g] = make_uint4(H0 | (H1 << 16), H2 | (H0 << 16),
                         H1 | (H2 << 16), L0 | (L1 << 16));   // k0..7
    rec1[g] = make_uint4(L2 | (ONEBF << 16), ONEBF | (sh << 16),
                         sl, 0u);                             // k8..15
}

// stage one 512-y chunk (both k-halves) into one LDS buffer.
// Layout MUST stay linear-contiguous in lane order (global_load_lds writes
// wave-uniform base + lane*16 — m104/m173). 4 loads/thread.
__device__ __forceinline__ void stage4(const uint4* __restrict__ r0,
                                       const uint4* __restrict__ r1,
                                       uint4* dst, int tid) {
    gl_lds16(r0 + tid,       dst + tid);             // kg=0, y 0..255
    gl_lds16(r0 + 256 + tid, dst + 256 + tid);       // kg=0, y 256..511
    gl_lds16(r1 + tid,       dst + YC + tid);        // kg=1, y 0..255
    gl_lds16(r1 + 256 + tid, dst + YC + 256 + tid);  // kg=1, y 256..511
}

// ---- main: per block, 128-x strip vs all 4096 y; row mins -> block sum
__global__ __launch_bounds__(T, 4) void chamfer_main(
    const float* __restrict__ pred, const float* __restrict__ target,
    const uint4* __restrict__ rec0, const uint4* __restrict__ rec1,
    float* __restrict__ bsum)
{
    __shared__ uint4 ldsy[2][2][YC];    // 32 KiB, [buf][kg][y]
    __shared__ float wsum[4];

    const int xb  = blockIdx.x;
    const int b   = blockIdx.y;
    const int dir = blockIdx.z;      // 0: x=pred,y=target(set0); 1: swapped
    const float* xsrc = (dir ? target : pred) + (size_t)b * NN * 3;
    const size_t ygbase = (size_t)dir * NPTS + (size_t)b * NN;
    const int tid  = threadIdx.x;
    const int lane = tid & 63, w = tid >> 6;
    const int kg   = lane >> 5, m = lane & 31;

    const uint4* r0 = rec0 + ygbase;
    const uint4* r1 = rec1 + ygbase;

    // prologue: chunk 0 DMA in flight while we build the A fragment
    stage4(r0, r1, &ldsy[0][0][0], tid);

    // A fragment (one 32-row strip per wave) — layout verified R6
    union U { uint4 q; bf16x8 v; };
    U au;
    {
        int xi = xb * XC + w * 32 + m;
        const float* xp = xsrc + (size_t)xi * 3;
        float x0 = xp[0], x1 = xp[1], x2 = xp[2];
        unsigned int h0 = f2bf(x0), h1 = f2bf(x1), h2 = f2bf(x2);
        unsigned int L0 = f2bf(x0 - bf2f(h0));
        unsigned int L1 = f2bf(x1 - bf2f(h1));
        unsigned int L2 = f2bf(x2 - bf2f(h2));
        float xsq = fmaf(x0, x0, fmaf(x1, x1, x2 * x2));
        unsigned int sh = f2bf(xsq);
        unsigned int sl = f2bf(xsq - bf2f(sh));
        au.q = make_uint4(kg ? (h2 | (sh << 16))    : (h0 | (h1 << 16)),
                          kg ? (sl | (ONEBF << 16)) : (h2 | (L0 << 16)),
                          kg ? ONEBF                : (L1 | (L2 << 16)),
                          kg ? 0u                   : (h0 | (h1 << 16)));
    }

    floatx16 acc, zacc;
#pragma unroll
    for (int r = 0; r < 16; ++r) { acc[r] = 3.402823466e38f; zacc[r] = 0.f; }

    for (int c = 0; c < NC; ++c) {
        const int buf = c & 1;
        if (c + 1 < NC) {
            // issue next chunk's DMA into the other buffer, then wait only
            // for the CURRENT chunk's 4 loads (oldest) — next 4 stay in
            // flight across the barrier (T4 counted vmcnt).
            stage4(r0 + (c + 1) * YC, r1 + (c + 1) * YC,
                   &ldsy[buf ^ 1][0][0], tid);
            asm volatile("s_waitcnt vmcnt(4)" ::: "memory");
        } else {
            asm volatile("s_waitcnt vmcnt(0)" ::: "memory");
        }
        __builtin_amdgcn_s_barrier();   // all waves' chunk-c DMA landed

#pragma unroll 2
        for (int t = 0; t < YC / 32; t += 2) {
            U bu0, bu1;
            bu0.q = ldsy[buf][kg][t * 32 + m];
            bu1.q = ldsy[buf][kg][t * 32 + 32 + m];
            floatx16 d0 = __builtin_amdgcn_mfma_f32_32x32x16_bf16(
                au.v, bu0.v, zacc, 0, 0, 0);
            floatx16 d1 = __builtin_amdgcn_mfma_f32_32x32x16_bf16(
                au.v, bu1.v, zacc, 0, 0, 0);
#pragma unroll
            for (int r = 0; r < 16; ++r)
                acc[r] = fminf(fminf(acc[r], d0[r]), d1[r]);   // v_min3
        }

        // all our ds_reads complete (results consumed by MFMA), then make
        // sure every wave is done reading buf before iter c+1 restages it
        asm volatile("s_waitcnt lgkmcnt(0)" ::: "memory");
        __builtin_amdgcn_s_barrier();
    }

    // row epilogue: min over 32 col-lanes, sum rows, one store per block
    float s = 0.f;
#pragma unroll
    for (int r = 0; r < 16; ++r) {
        float v = acc[r];
        v = fminf(v, __shfl_xor(v, 1, 64));
        v = fminf(v, __shfl_xor(v, 2, 64));
        v = fminf(v, __shfl_xor(v, 4, 64));
        v = fminf(v, __shfl_xor(v, 8, 64));
        v = fminf(v, __shfl_xor(v, 16, 64));   // all lanes in kg-half hold min
        s += fmaxf(v, 0.f);
    }
    s += __shfl_xor(s, 32, 64);                // combine the two kg halves
    if (lane == 0) wsum[w] = s;
    __syncthreads();
    if (tid == 0)
        bsum[(dir * BB + b) * NXB + xb] = wsum[0] + wsum[1] + wsum[2] + wsum[3];
}

// ---- final: sum 1024 block sums, scale, write scalar out (no atomics)
__global__ __launch_bounds__(T) void chamfer_final(
    const float* __restrict__ bsum, float* __restrict__ out)
{
    float s = 0.f;
    for (int i = threadIdx.x; i < NBLK; i += T) s += bsum[i];
#pragma unroll
    for (int off = 32; off > 0; off >>= 1)
        s += __shfl_down(s, off, 64);
    __shared__ float wsum[4];
    if ((threadIdx.x & 63) == 0) wsum[threadIdx.x >> 6] = s;
    __syncthreads();
    if (threadIdx.x == 0)
        out[0] = (wsum[0] + wsum[1] + wsum[2] + wsum[3]) * (1.0f / (BB * NN));
}

extern "C" void kernel_launch(void* const* d_in, const int* in_sizes, int n_in,
                              void* d_out, int out_size, void* d_ws, size_t ws_size,
                              hipStream_t stream) {
    const float* pred   = (const float*)d_in[0];
    const float* target = (const float*)d_in[1];
    // d_in[2] (batch, int64) ignored: sorted equal-size segments by construction.
    float* out  = (float*)d_out;
    uint4* rec0 = (uint4*)d_ws;                  // 2 MB
    uint4* rec1 = rec0 + 2 * NPTS;               // 2 MB
    float* bsum = (float*)(rec1 + 2 * NPTS);     // 4 KB

    chamfer_prep<<<2 * NPTS / T, T, 0, stream>>>(pred, target, rec0, rec1);
    dim3 grid(NXB, BB, 2);                       // 32 x 16 x 2 = 1024
    chamfer_main<<<grid, T, 0, stream>>>(pred, target, rec0, rec1, bsum);
    chamfer_final<<<1, T, 0, stream>>>(bsum, out);
}

// Round 2
// 83.514 us; speedup vs baseline: 1.0305x; 1.0305x over previous
//
#include <hip/hip_runtime.h>

// Chamfer distance via MFMA — R13: 64 rows per wave (XC=256).
// R12's async staging was NULL -> main was never staging-bound; revised
// per-CU pipe model says LDS ds_read_b128 is the dominant pipe
// (2048/CU x 12cy = 10.2us vs MFMA 1.7us, VALU-min3 3.4us). Fix: each
// wave owns TWO 32-row A-frags, so every B ds_read feeds 2 MFMAs ->
// LDS reads/CU halve (floor 5.1us). Blocks 1024->512 (fewer barriers,
// rec L2 re-reads 128->64 MiB). min3 pairing kept per-A-frag
// (acc=min3(acc,d0,d1)) so the VALU floor stays 3.4us.
// This is also the decisive experiment for the harness-fill theory: the
// timed 86us ~= 2 x 43.5us 256-MiB re-poison fills (only dispatches in
// top-5). If halving the dominant kernel pipe moves dur_us <3%, the
// floor is the harness re-poison, not our kernels.
// d2(i,j) = xsq_i + ysq_j - 2 x.y in one 32x32x16 bf16 MFMA via split-bf16
// K-slots (packing verified since R6, absmax 0.0):
//   A k0..15 = [xh0,xh1,xh2, xl0,xl1,xl2, xh0,xh1, xh2, xsqh,xsql, 1,1, 0,0,0]
//   B k0..15 = [-2yh0..2,   -2yh0..2,    -2yl0..2,     1,1, ysqh,ysql, 0,0,0]
// Zero atomics anywhere (R9 lesson).

typedef __attribute__((ext_vector_type(8))) short bf16x8;
typedef __attribute__((ext_vector_type(16))) float floatx16;

#define BB 16
#define NN 4096
#define T  256
#define NPTS (BB * NN)       // 65536 points per set
#define YC 512               // y per LDS chunk
#define NC (NN / YC)         // 8 chunks
#define XC 256               // x per block (4 waves x 64-row strip)
#define NXB (NN / XC)        // 16 x-blocks
#define NBLK (2 * BB * NXB)  // 512 main blocks
#define ONEBF 0x3F80u

__device__ __forceinline__ unsigned int f2bf(float f) {
    unsigned int u = __float_as_uint(f);
    u += 0x7fffu + ((u >> 16) & 1u);     // RNE to bf16
    return u >> 16;
}
__device__ __forceinline__ float bf2f(unsigned int h) {
    return __uint_as_float(h << 16);
}

// async 16B global->LDS DMA (no VGPR round-trip; compiler never auto-emits)
__device__ __forceinline__ void gl_lds16(const uint4* g, uint4* l) {
    __builtin_amdgcn_global_load_lds(
        (const __attribute__((address_space(1))) void*)g,
        (__attribute__((address_space(3))) void*)l, 16, 0, 0);
}

// ---- prep: build 32B y-records for both point sets (set0=target, set1=pred)
__global__ __launch_bounds__(T) void chamfer_prep(
    const float* __restrict__ pred, const float* __restrict__ target,
    uint4* __restrict__ rec0, uint4* __restrict__ rec1)
{
    int g = blockIdx.x * T + threadIdx.x;        // 0 .. 2*NPTS-1
    int set = g >> 16;                           // /NPTS
    int idx = g & (NPTS - 1);
    const float* yp = (set ? pred : target) + (size_t)idx * 3;
    float y0 = yp[0], y1 = yp[1], y2 = yp[2];
    unsigned int h0 = f2bf(y0), h1 = f2bf(y1), h2 = f2bf(y2);
    unsigned int H0 = f2bf(-2.f * bf2f(h0));
    unsigned int H1 = f2bf(-2.f * bf2f(h1));
    unsigned int H2 = f2bf(-2.f * bf2f(h2));
    unsigned int L0 = f2bf(-2.f * (y0 - bf2f(h0)));
    unsigned int L1 = f2bf(-2.f * (y1 - bf2f(h1)));
    unsigned int L2 = f2bf(-2.f * (y2 - bf2f(h2)));
    float ysq = fmaf(y0, y0, fmaf(y1, y1, y2 * y2));
    unsigned int sh = f2bf(ysq);
    unsigned int sl = f2bf(ysq - bf2f(sh));
    rec0[g] = make_uint4(H0 | (H1 << 16), H2 | (H0 << 16),
                         H1 | (H2 << 16), L0 | (L1 << 16));   // k0..7
    rec1[g] = make_uint4(L2 | (ONEBF << 16), ONEBF | (sh << 16),
                         sl, 0u);                             // k8..15
}

// stage one 512-y chunk (both k-halves) into one LDS buffer.
// Layout MUST stay linear-contiguous in lane order (global_load_lds writes
// wave-uniform base + lane*16 — m104/m173). 4 loads/thread.
__device__ __forceinline__ void stage4(const uint4* __restrict__ r0,
                                       const uint4* __restrict__ r1,
                                       uint4* dst, int tid) {
    gl_lds16(r0 + tid,       dst + tid);             // kg=0, y 0..255
    gl_lds16(r0 + 256 + tid, dst + 256 + tid);       // kg=0, y 256..511
    gl_lds16(r1 + tid,       dst + YC + tid);        // kg=1, y 0..255
    gl_lds16(r1 + 256 + tid, dst + YC + 256 + tid);  // kg=1, y 256..511
}

union U { uint4 q; bf16x8 v; };

// A fragment for one 32-row strip (layout verified R6)
__device__ __forceinline__ U build_a(const float* __restrict__ xsrc,
                                     int xi, int kg) {
    const float* xp = xsrc + (size_t)xi * 3;
    float x0 = xp[0], x1 = xp[1], x2 = xp[2];
    unsigned int h0 = f2bf(x0), h1 = f2bf(x1), h2 = f2bf(x2);
    unsigned int L0 = f2bf(x0 - bf2f(h0));
    unsigned int L1 = f2bf(x1 - bf2f(h1));
    unsigned int L2 = f2bf(x2 - bf2f(h2));
    float xsq = fmaf(x0, x0, fmaf(x1, x1, x2 * x2));
    unsigned int sh = f2bf(xsq);
    unsigned int sl = f2bf(xsq - bf2f(sh));
    U au;
    au.q = make_uint4(kg ? (h2 | (sh << 16))    : (h0 | (h1 << 16)),
                      kg ? (sl | (ONEBF << 16)) : (h2 | (L0 << 16)),
                      kg ? ONEBF                : (L1 | (L2 << 16)),
                      kg ? 0u                   : (h0 | (h1 << 16)));
    return au;
}

// ---- main: per block, 256-x strip vs all 4096 y; row mins -> block sum
__global__ __launch_bounds__(T, 2) void chamfer_main(
    const float* __restrict__ pred, const float* __restrict__ target,
    const uint4* __restrict__ rec0, const uint4* __restrict__ rec1,
    float* __restrict__ bsum)
{
    __shared__ uint4 ldsy[2][2][YC];    // 32 KiB, [buf][kg][y]
    __shared__ float wsum[4];

    const int xb  = blockIdx.x;
    const int b   = blockIdx.y;
    const int dir = blockIdx.z;      // 0: x=pred,y=target(set0); 1: swapped
    const float* xsrc = (dir ? target : pred) + (size_t)b * NN * 3;
    const size_t ygbase = (size_t)dir * NPTS + (size_t)b * NN;
    const int tid  = threadIdx.x;
    const int lane = tid & 63, w = tid >> 6;
    const int kg   = lane >> 5, m = lane & 31;

    const uint4* r0 = rec0 + ygbase;
    const uint4* r1 = rec1 + ygbase;

    // prologue: chunk 0 DMA in flight while we build the A fragments
    stage4(r0, r1, &ldsy[0][0][0], tid);

    const int xrow = xb * XC + w * 64 + m;
    U au0 = build_a(xsrc, xrow,      kg);
    U au1 = build_a(xsrc, xrow + 32, kg);

    floatx16 acc0, acc1, zacc;
#pragma unroll
    for (int r = 0; r < 16; ++r) {
        acc0[r] = 3.402823466e38f; acc1[r] = 3.402823466e38f; zacc[r] = 0.f;
    }

    for (int c = 0; c < NC; ++c) {
        const int buf = c & 1;
        if (c + 1 < NC) {
            // issue next chunk's DMA into the other buffer, then wait only
            // for the CURRENT chunk's 4 loads (oldest) — next 4 stay in
            // flight across the barrier (T4 counted vmcnt).
            stage4(r0 + (c + 1) * YC, r1 + (c + 1) * YC,
                   &ldsy[buf ^ 1][0][0], tid);
            asm volatile("s_waitcnt vmcnt(4)" ::: "memory");
        } else {
            asm volatile("s_waitcnt vmcnt(0)" ::: "memory");
        }
        __builtin_amdgcn_s_barrier();   // all waves' chunk-c DMA landed

#pragma unroll 2
        for (int t = 0; t < YC / 32; t += 2) {
            U bu0, bu1;
            bu0.q = ldsy[buf][kg][t * 32 + m];
            bu1.q = ldsy[buf][kg][t * 32 + 32 + m];
            // each ds_read feeds TWO MFMAs (au0 and au1)
            floatx16 d0 = __builtin_amdgcn_mfma_f32_32x32x16_bf16(
                au0.v, bu0.v, zacc, 0, 0, 0);
            floatx16 d1 = __builtin_amdgcn_mfma_f32_32x32x16_bf16(
                au0.v, bu1.v, zacc, 0, 0, 0);
            floatx16 d2 = __builtin_amdgcn_mfma_f32_32x32x16_bf16(
                au1.v, bu0.v, zacc, 0, 0, 0);
            floatx16 d3 = __builtin_amdgcn_mfma_f32_32x32x16_bf16(
                au1.v, bu1.v, zacc, 0, 0, 0);
#pragma unroll
            for (int r = 0; r < 16; ++r) {
                acc0[r] = fminf(fminf(acc0[r], d0[r]), d1[r]);   // v_min3
                acc1[r] = fminf(fminf(acc1[r], d2[r]), d3[r]);   // v_min3
            }
        }

        // all our ds_reads complete, then make sure every wave is done
        // reading buf before iter c+1 restages it
        asm volatile("s_waitcnt lgkmcnt(0)" ::: "memory");
        __builtin_amdgcn_s_barrier();
    }

    // row epilogue: min over 32 col-lanes, sum rows, one store per block
    float s = 0.f;
#pragma unroll
    for (int r = 0; r < 16; ++r) {
        float v = acc0[r];
        v = fminf(v, __shfl_xor(v, 1, 64));
        v = fminf(v, __shfl_xor(v, 2, 64));
        v = fminf(v, __shfl_xor(v, 4, 64));
        v = fminf(v, __shfl_xor(v, 8, 64));
        v = fminf(v, __shfl_xor(v, 16, 64));   // all lanes in kg-half hold min
        s += fmaxf(v, 0.f);
    }
#pragma unroll
    for (int r = 0; r < 16; ++r) {
        float v = acc1[r];
        v = fminf(v, __shfl_xor(v, 1, 64));
        v = fminf(v, __shfl_xor(v, 2, 64));
        v = fminf(v, __shfl_xor(v, 4, 64));
        v = fminf(v, __shfl_xor(v, 8, 64));
        v = fminf(v, __shfl_xor(v, 16, 64));
        s += fmaxf(v, 0.f);
    }
    s += __shfl_xor(s, 32, 64);                // combine the two kg halves
    if (lane == 0) wsum[w] = s;
    __syncthreads();
    if (tid == 0)
        bsum[(dir * BB + b) * NXB + xb] = wsum[0] + wsum[1] + wsum[2] + wsum[3];
}

// ---- final: sum 512 block sums, scale, write scalar out (no atomics)
__global__ __launch_bounds__(T) void chamfer_final(
    const float* __restrict__ bsum, float* __restrict__ out)
{
    float s = 0.f;
    for (int i = threadIdx.x; i < NBLK; i += T) s += bsum[i];
#pragma unroll
    for (int off = 32; off > 0; off >>= 1)
        s += __shfl_down(s, off, 64);
    __shared__ float wsum[4];
    if ((threadIdx.x & 63) == 0) wsum[threadIdx.x >> 6] = s;
    __syncthreads();
    if (threadIdx.x == 0)
        out[0] = (wsum[0] + wsum[1] + wsum[2] + wsum[3]) * (1.0f / (BB * NN));
}

extern "C" void kernel_launch(void* const* d_in, const int* in_sizes, int n_in,
                              void* d_out, int out_size, void* d_ws, size_t ws_size,
                              hipStream_t stream) {
    const float* pred   = (const float*)d_in[0];
    const float* target = (const float*)d_in[1];
    // d_in[2] (batch, int64) ignored: sorted equal-size segments by construction.
    float* out  = (float*)d_out;
    uint4* rec0 = (uint4*)d_ws;                  // 2 MB
    uint4* rec1 = rec0 + 2 * NPTS;               // 2 MB
    float* bsum = (float*)(rec1 + 2 * NPTS);     // 2 KB

    chamfer_prep<<<2 * NPTS / T, T, 0, stream>>>(pred, target, rec0, rec1);
    dim3 grid(NXB, BB, 2);                       // 16 x 16 x 2 = 512
    chamfer_main<<<grid, T, 0, stream>>>(pred, target, rec0, rec1, bsum);
    chamfer_final<<<1, T, 0, stream>>>(bsum, out);
}